// Round 2
// baseline (5979.111 us; speedup 1.0000x reference)
//
#include <hip/hip_runtime.h>
#include <hip/hip_bf16.h>

#define SEQn 70
#define Bn 128
#define En 512
#define Hn 1024
#define Vn 10000
#define VPADn 10240
#define Mn (SEQn*Bn)      // 8960
#define H3n (3*Hn)        // 3072
#define BHn (Bn*Hn)       // 131072
#define NBLK 192

typedef __hip_bfloat16 bf16;
typedef __attribute__((ext_vector_type(8))) short short8;
typedef __attribute__((ext_vector_type(4))) float f32x4;

__device__ __forceinline__ bf16 f2bf(float x){ return __float2bfloat16(x); }
__device__ __forceinline__ float bf2f(bf16 x){ return __bfloat162float(x); }

__device__ __forceinline__ void gl_lds16(const void* g, void* l){
  __builtin_amdgcn_global_load_lds((const __attribute__((address_space(1))) unsigned int*)g,
                                   (__attribute__((address_space(3))) unsigned int*)l, 16, 0, 0);
}

// ---------------- small prep kernels ----------------

__global__ void cat3_w(const float* __restrict__ a, const float* __restrict__ b,
                       const float* __restrict__ c, bf16* __restrict__ d, int n){
  int i = blockIdx.x * 256 + threadIdx.x;
  if (i >= 3*n) return;
  const float* s = (i < n) ? a : ((i < 2*n) ? b : c);
  int off = (i < n) ? i : ((i < 2*n) ? i - n : i - 2*n);
  d[i] = f2bf(s[off]);
}

__global__ void cat3_f(const float* __restrict__ a, const float* __restrict__ b,
                       const float* __restrict__ c, float* __restrict__ d, int n){
  int i = blockIdx.x * 256 + threadIdx.x;
  if (i >= 3*n) return;
  d[i] = (i < n) ? a[i] : ((i < 2*n) ? b[i - n] : c[i - 2*n]);
}

__global__ void f2b_k(const float* __restrict__ s, bf16* __restrict__ d, int n){
  int i = blockIdx.x * 256 + threadIdx.x;
  if (i < n) d[i] = f2bf(s[i]);
}

__global__ void conv_outw(const float* __restrict__ s, bf16* __restrict__ d){
  long i = (long)blockIdx.x * 256 + threadIdx.x;
  if (i >= (long)VPADn * Hn) return;
  int row = (int)(i >> 10);
  d[i] = (row < Vn) ? f2bf(s[i]) : f2bf(0.f);
}

__global__ void embed_k(const int* __restrict__ idx, const float* __restrict__ eW,
                        bf16* __restrict__ out){
  const int sb = blockIdx.x;
  const int t = idx[sb];
  const float* s = eW + (long)t * En;
  bf16* d = out + (long)sb * En;
  for (int e = threadIdx.x; e < En; e += 256) d[e] = f2bf(s[e]);
}

// ---------------- GEMM: C[M,N] = A[M,K] * B[N,K]^T + bias ----------------
// (round-1 structure: 128x128 tile, BK=64, 4 waves of 64x64, verified)

template<bool OB, bool NB>
__global__ __launch_bounds__(256)
void gemm_bt(const bf16* __restrict__ A, const bf16* __restrict__ Bm,
             const float* __restrict__ bias, void* __restrict__ C,
             int K, int ldc, int nvalid)
{
  __shared__ __align__(16) bf16 As[128*64];
  __shared__ __align__(16) bf16 Bs[128*64];
  const int tid = threadIdx.x;
  const int l = tid & 63, w = tid >> 6;
  const int lr = l & 15, lk = l >> 4;
  const int wm = (w >> 1) * 64, wn = (w & 1) * 64;
  const int mt = blockIdx.y, nt = blockIdx.x;
  const bf16* Ag = A + (long)mt * 128 * K;
  const bf16* Bg = Bm + (long)nt * 128 * K;

  f32x4 acc[4][4] = {};

  for (int kb = 0; kb < K; kb += 64) {
#pragma unroll
    for (int r = 0; r < 4; ++r) {
      const int u = r * 256 + tid;
      const int row = u >> 3, kus = (u & 7) ^ (row & 7);
      gl_lds16(Ag + (long)row * K + kb + kus * 8, (char*)As + (r * 256 + w * 64) * 16);
    }
#pragma unroll
    for (int r = 0; r < 4; ++r) {
      const int u = r * 256 + tid;
      const int row = u >> 3, kus = (u & 7) ^ (row & 7);
      gl_lds16(Bg + (long)row * K + kb + kus * 8, (char*)Bs + (r * 256 + w * 64) * 16);
    }
    __syncthreads();
#pragma unroll
    for (int kh = 0; kh < 2; ++kh) {
      const int ku = kh * 4 + lk;
      short8 af[4], bfv[4];
#pragma unroll
      for (int i = 0; i < 4; ++i) {
        const int ar = wm + i * 16 + lr;
        af[i]  = *(const short8*)((const char*)As + ar * 128 + ((ku ^ (ar & 7)) * 16));
        const int br = wn + i * 16 + lr;
        bfv[i] = *(const short8*)((const char*)Bs + br * 128 + ((ku ^ (br & 7)) * 16));
      }
#pragma unroll
      for (int i = 0; i < 4; ++i)
#pragma unroll
        for (int j = 0; j < 4; ++j)
          acc[i][j] = __builtin_amdgcn_mfma_f32_16x16x32_bf16(af[i], bfv[j], acc[i][j], 0, 0, 0);
    }
    __syncthreads();
  }

#pragma unroll
  for (int i = 0; i < 4; ++i) {
#pragma unroll
    for (int j = 0; j < 4; ++j) {
      const int col = nt * 128 + wn + j * 16 + lr;
      const bool cok = (!NB) || (col < nvalid);
      const float bv = cok ? bias[col] : 0.f;
      const int row = mt * 128 + wm + i * 16 + lk * 4;
      if (cok) {
#pragma unroll
        for (int r = 0; r < 4; ++r) {
          const float v = acc[i][j][r] + bv;
          if (OB) ((bf16*)C)[(long)(row + r) * ldc + col] = f2bf(v);
          else    ((float*)C)[(long)(row + r) * ldc + col] = v;
        }
      }
    }
  }
}

// ---------------- persistent pipelined GRU ----------------
// 192 blocks x 512 threads. Role = blockIdx.x/64:
//   0: layer-0 recurrence  (stage s computes h0[t], t=s)
//   1: layer-1 input proj  (stage s computes xg1[t], t=s-1, overwrites xg slot)
//   2: layer-1 recurrence  (stage s computes h1[t], t=s-2)
// Weight slice (48 rows x 1024) LDS-resident for the whole sequence.
// f32 h-carry lives in registers (same wave owns same cells every stage).
// ys0/ys1 layout: slot t+1 = h[t], slot 0 = bf16(h_init).

__device__ __forceinline__ void stage_chunk(const bf16* __restrict__ Asrc, int c,
                                            char* dst, int tid, int wbase) {
#pragma unroll
  for (int it = 0; it < 2; ++it) {
    const int L = it * 512 + tid;
    const int row = L >> 3, up = L & 7, u = up ^ (row & 7);
    gl_lds16(Asrc + (size_t)row * 1024 + (size_t)(c * 8 + u) * 8,
             dst + (it * 512 + wbase) * 16);
  }
}

__global__ __launch_bounds__(512, 1)
void gru_persist(const bf16* __restrict__ Wh0, const bf16* __restrict__ Wi1,
                 const bf16* __restrict__ Wh1, const float* __restrict__ b1,
                 const float* __restrict__ hidden, bf16* __restrict__ xg,
                 bf16* __restrict__ ys0, bf16* __restrict__ ys1,
                 float* __restrict__ hT, unsigned* __restrict__ bar)
{
  __shared__ __align__(16) char smem[131072];   // W: 96KB | A dbuf: 2x16KB
  char* Ab0 = smem + 98304;
  char* Ab1 = smem + 98304 + 16384;

  const int tid = threadIdx.x;
  const int lane = tid & 63, wid = tid >> 6;
  const int wbase = tid & ~63;
  const int lr = lane & 15, lk = lane >> 4;
  const int role = blockIdx.x >> 6, nb = blockIdx.x & 63;
  const int col0 = nb * 16;
  const int col = col0 + lr;

  // preload 48x1024 bf16 weight slice into LDS (swizzled: unit ^= row&7)
  const bf16* Wsrc = (role == 0) ? Wh0 : ((role == 1) ? Wi1 : Wh1);
#pragma unroll
  for (int it = 0; it < 12; ++it) {
    const int L = it * 512 + tid;
    const int row = L >> 7, up = L & 127, u = up ^ (row & 7);
    const int g3 = row >> 4, rr = row & 15;
    gl_lds16(Wsrc + ((size_t)(g3 * Hn + col0 + rr)) * Hn + (size_t)u * 8,
             smem + (it * 512 + wbase) * 16);
  }

  f32x4 hreg = {};
  float bv[3] = {};
  if (role != 1) {
    const float* hsrc = hidden + (role == 2 ? BHn : 0);
#pragma unroll
    for (int r = 0; r < 4; ++r)
      hreg[r] = hsrc[(size_t)(wid * 16 + lk * 4 + r) * Hn + col];
  } else {
#pragma unroll
    for (int g = 0; g < 3; ++g) bv[g] = b1[g * Hn + col];
  }
  asm volatile("s_waitcnt vmcnt(0)" ::: "memory");
  __syncthreads();

  for (int s = 0; s < 72; ++s) {
    const int t = s - role;
    if (t >= 0 && t < SEQn) {
      const bf16* Asrc = (role == 0) ? (ys0 + (size_t)t * BHn)
                       : (role == 1) ? (ys0 + (size_t)(t + 1) * BHn)
                                     : (ys1 + (size_t)t * BHn);
      f32x4 acc[3] = {};
      stage_chunk(Asrc, 0, Ab0, tid, wbase);
      for (int c = 0; c < 16; ++c) {
        char* cur = (c & 1) ? Ab1 : Ab0;
        char* nxt = (c & 1) ? Ab0 : Ab1;
        if (c < 15) {
          stage_chunk(Asrc, c + 1, nxt, tid, wbase);
          asm volatile("s_waitcnt vmcnt(2)" ::: "memory");
        } else {
          asm volatile("s_waitcnt vmcnt(0)" ::: "memory");
        }
        asm volatile("s_barrier" ::: "memory");
#pragma unroll
        for (int kh = 0; kh < 2; ++kh) {
          const int ku = kh * 4 + lk;
          const int arow = wid * 16 + lr;
          short8 a = *(const short8*)(cur + ((arow * 8 + (ku ^ (arow & 7))) * 16));
#pragma unroll
          for (int g = 0; g < 3; ++g) {
            const int brow = g * 16 + lr;
            short8 b = *(const short8*)(smem + ((brow * 128 + ((c * 8 + ku) ^ (brow & 7))) * 16));
            acc[g] = __builtin_amdgcn_mfma_f32_16x16x32_bf16(a, b, acc[g], 0, 0, 0);
          }
        }
        asm volatile("s_barrier" ::: "memory");
      }
      // epilogue
      if (role == 1) {
#pragma unroll
        for (int g = 0; g < 3; ++g)
#pragma unroll
          for (int r = 0; r < 4; ++r) {
            const int row = wid * 16 + lk * 4 + r;
            xg[((size_t)t * Bn + row) * H3n + g * Hn + col] = f2bf(acc[g][r] + bv[g]);
          }
      } else {
        bf16* ydst = ((role == 0) ? ys0 : ys1) + (size_t)(t + 1) * BHn;
        const bf16* xsrc = xg + (size_t)t * Bn * H3n;
#pragma unroll
        for (int r = 0; r < 4; ++r) {
          const int row = wid * 16 + lk * 4 + r;
          const float xr = bf2f(xsrc[(size_t)row * H3n + col]);
          const float xz = bf2f(xsrc[(size_t)row * H3n + Hn + col]);
          const float xh = bf2f(xsrc[(size_t)row * H3n + 2 * Hn + col]);
          const float rg = 1.f / (1.f + __expf(-(xr + acc[0][r])));
          const float zg = 1.f / (1.f + __expf(-(xz + acc[1][r])));
          const float hc = tanhf(xh + rg * acc[2][r]);
          const float hn = (1.f - zg) * hc + zg * hreg[r];
          hreg[r] = hn;
          ydst[(size_t)row * Hn + col] = f2bf(hn);
          if (t == SEQn - 1)
            hT[(role == 0 ? 0 : BHn) + (size_t)row * Hn + col] = hn;
        }
      }
    }
    // ---- device-scope grid barrier ----
    __threadfence();
    __syncthreads();
    if (tid == 0) {
      __hip_atomic_fetch_add(bar, 1u, __ATOMIC_RELEASE, __HIP_MEMORY_SCOPE_AGENT);
      const unsigned tgt = (unsigned)((s + 1) * NBLK);
      while (__hip_atomic_load(bar, __ATOMIC_ACQUIRE, __HIP_MEMORY_SCOPE_AGENT) < tgt)
        __builtin_amdgcn_s_sleep(8);
    }
    __syncthreads();
    __threadfence();
  }
}

// ---------------- launch ----------------

extern "C" void kernel_launch(void* const* d_in, const int* in_sizes, int n_in,
                              void* d_out, int out_size, void* d_ws, size_t ws_size,
                              hipStream_t stream)
{
  (void)in_sizes; (void)n_in; (void)out_size; (void)ws_size;
  const int*   inp    = (const int*)d_in[0];
  const float* hidden = (const float*)d_in[1];
  const float* embW   = (const float*)d_in[2];
  const float* outW   = (const float*)d_in[3];
  const float* outb   = (const float*)d_in[4];

  char* p = (char*)d_ws;
  auto take = [&](size_t n){ char* q = p; p += (n + 255) & ~(size_t)255; return q; };
  bf16*  l0Wi = (bf16*) take((size_t)H3n*En*2);
  bf16*  l0Wh = (bf16*) take((size_t)H3n*Hn*2);
  bf16*  l1Wi = (bf16*) take((size_t)H3n*Hn*2);
  bf16*  l1Wh = (bf16*) take((size_t)H3n*Hn*2);
  bf16*  oW   = (bf16*) take((size_t)VPADn*Hn*2);
  float* b0   = (float*)take((size_t)H3n*4);
  float* b1   = (float*)take((size_t)H3n*4);
  bf16*  emb  = (bf16*) take((size_t)Mn*En*2);
  bf16*  xg   = (bf16*) take((size_t)Mn*H3n*2);
  bf16*  ys0  = (bf16*) take((size_t)(SEQn+1)*BHn*2);
  bf16*  ys1  = (bf16*) take((size_t)(SEQn+1)*BHn*2);
  unsigned* bar = (unsigned*)take(256);

  // weight/bias prep (bf16, gate-concatenated [r;z;h])
  cat3_w<<<dim3((3*Hn*En+255)/256),256,0,stream>>>((const float*)d_in[5],(const float*)d_in[6],(const float*)d_in[7], l0Wi, Hn*En);
  cat3_w<<<dim3((3*Hn*Hn+255)/256),256,0,stream>>>((const float*)d_in[8],(const float*)d_in[9],(const float*)d_in[10], l0Wh, Hn*Hn);
  cat3_w<<<dim3((3*Hn*Hn+255)/256),256,0,stream>>>((const float*)d_in[14],(const float*)d_in[15],(const float*)d_in[16], l1Wi, Hn*Hn);
  cat3_w<<<dim3((3*Hn*Hn+255)/256),256,0,stream>>>((const float*)d_in[17],(const float*)d_in[18],(const float*)d_in[19], l1Wh, Hn*Hn);
  conv_outw<<<dim3((unsigned)(((long)VPADn*Hn+255)/256)),256,0,stream>>>(outW, oW);
  cat3_f<<<dim3((H3n+255)/256),256,0,stream>>>((const float*)d_in[11],(const float*)d_in[12],(const float*)d_in[13], b0, Hn);
  cat3_f<<<dim3((H3n+255)/256),256,0,stream>>>((const float*)d_in[20],(const float*)d_in[21],(const float*)d_in[22], b1, Hn);
  f2b_k<<<dim3((BHn+255)/256),256,0,stream>>>(hidden, ys0, BHn);          // ys0 slot 0 = h0 init
  f2b_k<<<dim3((BHn+255)/256),256,0,stream>>>(hidden + BHn, ys1, BHn);    // ys1 slot 0 = h1 init
  embed_k<<<dim3(Mn),256,0,stream>>>(inp, embW, emb);
  hipMemsetAsync(bar, 0, 256, stream);

  // layer-0 input projection (xg slots hold xg0; role B overwrites per-stage)
  gemm_bt<true,false><<<dim3(H3n/128, Mn/128),256,0,stream>>>(emb, l0Wi, b0, xg, En, H3n, H3n);

  // both recurrences + layer-1 input projection, fully pipelined
  float* hT = (float*)d_out + (size_t)SEQn * Bn * Vn;
  gru_persist<<<dim3(NBLK), 512, 0, stream>>>(l0Wh, l1Wi, l1Wh, b1, hidden,
                                              xg, ys0, ys1, hT, bar);

  // logits: ys1 slots 1..70 are h1[0..69]
  gemm_bt<false,true><<<dim3(VPADn/128, Mn/128),256,0,stream>>>(ys1 + BHn, oW, outb, d_out, Hn, Vn, Vn);
}

// Round 3
// 1816.127 us; speedup vs baseline: 3.2922x; 3.2922x over previous
//
#include <hip/hip_runtime.h>
#include <hip/hip_bf16.h>

#define SEQn 70
#define Bn 128
#define En 512
#define Hn 1024
#define Vn 10000
#define VPADn 10240
#define Mn (SEQn*Bn)      // 8960
#define H3n (3*Hn)        // 3072
#define BHn (Bn*Hn)       // 131072
#define NBLK 192

typedef __hip_bfloat16 bf16;
typedef __attribute__((ext_vector_type(8))) short short8;
typedef __attribute__((ext_vector_type(4))) float f32x4;

__device__ __forceinline__ bf16 f2bf(float x){ return __float2bfloat16(x); }
__device__ __forceinline__ float bf2f(bf16 x){ return __bfloat162float(x); }

__device__ __forceinline__ void gl_lds16(const void* g, void* l){
  __builtin_amdgcn_global_load_lds((const __attribute__((address_space(1))) unsigned int*)g,
                                   (__attribute__((address_space(3))) unsigned int*)l, 16, 0, 0);
}

// ---------------- small prep kernels ----------------

__global__ void cat3_w(const float* __restrict__ a, const float* __restrict__ b,
                       const float* __restrict__ c, bf16* __restrict__ d, int n){
  int i = blockIdx.x * 256 + threadIdx.x;
  if (i >= 3*n) return;
  const float* s = (i < n) ? a : ((i < 2*n) ? b : c);
  int off = (i < n) ? i : ((i < 2*n) ? i - n : i - 2*n);
  d[i] = f2bf(s[off]);
}

__global__ void cat3_f(const float* __restrict__ a, const float* __restrict__ b,
                       const float* __restrict__ c, float* __restrict__ d, int n){
  int i = blockIdx.x * 256 + threadIdx.x;
  if (i >= 3*n) return;
  d[i] = (i < n) ? a[i] : ((i < 2*n) ? b[i - n] : c[i - 2*n]);
}

__global__ void f2b_k(const float* __restrict__ s, bf16* __restrict__ d, int n){
  int i = blockIdx.x * 256 + threadIdx.x;
  if (i < n) d[i] = f2bf(s[i]);
}

__global__ void conv_outw(const float* __restrict__ s, bf16* __restrict__ d){
  long i = (long)blockIdx.x * 256 + threadIdx.x;
  if (i >= (long)VPADn * Hn) return;
  int row = (int)(i >> 10);
  d[i] = (row < Vn) ? f2bf(s[i]) : f2bf(0.f);
}

__global__ void embed_k(const int* __restrict__ idx, const float* __restrict__ eW,
                        bf16* __restrict__ out){
  const int sb = blockIdx.x;
  const int t = idx[sb];
  const float* s = eW + (long)t * En;
  bf16* d = out + (long)sb * En;
  for (int e = threadIdx.x; e < En; e += 256) d[e] = f2bf(s[e]);
}

// ---------------- GEMM: C[M,N] = A[M,K] * B[N,K]^T + bias ----------------
// (round-1 structure: 128x128 tile, BK=64, 4 waves of 64x64, verified)

template<bool OB, bool NB>
__global__ __launch_bounds__(256)
void gemm_bt(const bf16* __restrict__ A, const bf16* __restrict__ Bm,
             const float* __restrict__ bias, void* __restrict__ C,
             int K, int ldc, int nvalid)
{
  __shared__ __align__(16) bf16 As[128*64];
  __shared__ __align__(16) bf16 Bs[128*64];
  const int tid = threadIdx.x;
  const int l = tid & 63, w = tid >> 6;
  const int lr = l & 15, lk = l >> 4;
  const int wm = (w >> 1) * 64, wn = (w & 1) * 64;
  const int mt = blockIdx.y, nt = blockIdx.x;
  const bf16* Ag = A + (long)mt * 128 * K;
  const bf16* Bg = Bm + (long)nt * 128 * K;

  f32x4 acc[4][4] = {};

  for (int kb = 0; kb < K; kb += 64) {
#pragma unroll
    for (int r = 0; r < 4; ++r) {
      const int u = r * 256 + tid;
      const int row = u >> 3, kus = (u & 7) ^ (row & 7);
      gl_lds16(Ag + (long)row * K + kb + kus * 8, (char*)As + (r * 256 + w * 64) * 16);
    }
#pragma unroll
    for (int r = 0; r < 4; ++r) {
      const int u = r * 256 + tid;
      const int row = u >> 3, kus = (u & 7) ^ (row & 7);
      gl_lds16(Bg + (long)row * K + kb + kus * 8, (char*)Bs + (r * 256 + w * 64) * 16);
    }
    __syncthreads();
#pragma unroll
    for (int kh = 0; kh < 2; ++kh) {
      const int ku = kh * 4 + lk;
      short8 af[4], bfv[4];
#pragma unroll
      for (int i = 0; i < 4; ++i) {
        const int ar = wm + i * 16 + lr;
        af[i]  = *(const short8*)((const char*)As + ar * 128 + ((ku ^ (ar & 7)) * 16));
        const int br = wn + i * 16 + lr;
        bfv[i] = *(const short8*)((const char*)Bs + br * 128 + ((ku ^ (br & 7)) * 16));
      }
#pragma unroll
      for (int i = 0; i < 4; ++i)
#pragma unroll
        for (int j = 0; j < 4; ++j)
          acc[i][j] = __builtin_amdgcn_mfma_f32_16x16x32_bf16(af[i], bfv[j], acc[i][j], 0, 0, 0);
    }
    __syncthreads();
  }

#pragma unroll
  for (int i = 0; i < 4; ++i) {
#pragma unroll
    for (int j = 0; j < 4; ++j) {
      const int col = nt * 128 + wn + j * 16 + lr;
      const bool cok = (!NB) || (col < nvalid);
      const float bv = cok ? bias[col] : 0.f;
      const int row = mt * 128 + wm + i * 16 + lk * 4;
      if (cok) {
#pragma unroll
        for (int r = 0; r < 4; ++r) {
          const float v = acc[i][j][r] + bv;
          if (OB) ((bf16*)C)[(long)(row + r) * ldc + col] = f2bf(v);
          else    ((float*)C)[(long)(row + r) * ldc + col] = v;
        }
      }
    }
  }
}

// ---------------- persistent pipelined GRU ----------------
// 192 blocks x 512 threads. Role = blockIdx.x/64:
//   0: layer-0 recurrence  (stage s computes h0[t], t=s)
//   1: layer-1 input proj  (stage s computes xg1[t], t=s-1, overwrites xg slot)
//   2: layer-1 recurrence  (stage s computes h1[t], t=s-2)
// Weights (48 rows x 1024, 96KB) LDS-resident for the whole sequence.
// A (h state) goes GLOBAL -> REGISTERS directly (no cross-wave reuse -> LDS
// staging was pure overhead); no barriers inside the K loop.
// Grid barrier: single release-fence + relaxed arrive + relaxed spin +
// single acquire-fence, all executed by tid0 only (2 cache ops/block/stage).

#define LOADQ(buf, base)                                                     \
  _Pragma("unroll")                                                          \
  for (int q = 0; q < 8; ++q)                                                \
    buf[q] = *(const short8*)(Arow + ((base) + q) * 32 + lk * 8);

#define MFMAQ(buf, base)                                                     \
  _Pragma("unroll")                                                          \
  for (int q = 0; q < 8; ++q) {                                              \
    _Pragma("unroll")                                                        \
    for (int g = 0; g < 3; ++g) {                                            \
      const int brow = g * 16 + lr;                                          \
      const short8 bfrag = *(const short8*)(smem +                           \
          (size_t)(brow * 128 + ((((base) + q) * 4 + lk) ^ (brow & 7))) * 16); \
      acc[g] = __builtin_amdgcn_mfma_f32_16x16x32_bf16(buf[q], bfrag, acc[g], 0, 0, 0); \
    }                                                                        \
  }

__global__ __launch_bounds__(512, 2)
void gru_persist(const bf16* __restrict__ Wh0, const bf16* __restrict__ Wi1,
                 const bf16* __restrict__ Wh1, const float* __restrict__ b1,
                 const float* __restrict__ hidden, bf16* __restrict__ xg,
                 bf16* __restrict__ ys0, bf16* __restrict__ ys1,
                 float* __restrict__ hT, unsigned* __restrict__ bar)
{
  __shared__ __align__(16) char smem[98304];   // 48 x 1024 bf16 weights, swizzled

  const int tid = threadIdx.x;
  const int lane = tid & 63, wid = tid >> 6;
  const int wbase = tid & ~63;
  const int lr = lane & 15, lk = lane >> 4;
  const int role = blockIdx.x >> 6, nb = blockIdx.x & 63;
  const int col0 = nb * 16;
  const int col = col0 + lr;

  // preload 48x1024 bf16 weight slice into LDS (swizzled: unit ^= row&7)
  const bf16* Wsrc = (role == 0) ? Wh0 : ((role == 1) ? Wi1 : Wh1);
#pragma unroll
  for (int it = 0; it < 12; ++it) {
    const int L = it * 512 + tid;
    const int row = L >> 7, up = L & 127, u = up ^ (row & 7);
    const int g3 = row >> 4, rr = row & 15;
    gl_lds16(Wsrc + ((size_t)(g3 * Hn + col0 + rr)) * Hn + (size_t)u * 8,
             smem + (it * 512 + wbase) * 16);
  }

  f32x4 hreg = {};
  float bv[3] = {};
  if (role != 1) {
    const float* hsrc = hidden + (role == 2 ? BHn : 0);
#pragma unroll
    for (int r = 0; r < 4; ++r)
      hreg[r] = hsrc[(size_t)(wid * 16 + lk * 4 + r) * Hn + col];
  } else {
#pragma unroll
    for (int g = 0; g < 3; ++g) bv[g] = b1[g * Hn + col];
  }
  asm volatile("s_waitcnt vmcnt(0)" ::: "memory");
  __syncthreads();

  const int arow = wid * 16 + lr;

  for (int s = 0; s < 72; ++s) {
    const int t = s - role;
    if (t >= 0 && t < SEQn) {
      const bf16* Asrc = (role == 0) ? (ys0 + (size_t)t * BHn)
                       : (role == 1) ? (ys0 + (size_t)(t + 1) * BHn)
                                     : (ys1 + (size_t)t * BHn);
      const bf16* Arow = Asrc + (size_t)arow * Hn;
      f32x4 acc[3] = {};
      short8 aA[8], aB[8];
      LOADQ(aA, 0)
      LOADQ(aB, 8)
      MFMAQ(aA, 0)
      LOADQ(aA, 16)
      MFMAQ(aB, 8)
      LOADQ(aB, 24)
      MFMAQ(aA, 16)
      MFMAQ(aB, 24)

      // epilogue
      if (role == 1) {
#pragma unroll
        for (int g = 0; g < 3; ++g)
#pragma unroll
          for (int r = 0; r < 4; ++r) {
            const int row = wid * 16 + lk * 4 + r;
            xg[((size_t)t * Bn + row) * H3n + g * Hn + col] = f2bf(acc[g][r] + bv[g]);
          }
      } else {
        bf16* ydst = ((role == 0) ? ys0 : ys1) + (size_t)(t + 1) * BHn;
        const bf16* xsrc = xg + (size_t)t * Bn * H3n;
#pragma unroll
        for (int r = 0; r < 4; ++r) {
          const int row = wid * 16 + lk * 4 + r;
          const float xr = bf2f(xsrc[(size_t)row * H3n + col]);
          const float xz = bf2f(xsrc[(size_t)row * H3n + Hn + col]);
          const float xh = bf2f(xsrc[(size_t)row * H3n + 2 * Hn + col]);
          const float rg = 1.f / (1.f + __expf(-(xr + acc[0][r])));
          const float zg = 1.f / (1.f + __expf(-(xz + acc[1][r])));
          const float hc = tanhf(xh + rg * acc[2][r]);
          const float hn = (1.f - zg) * hc + zg * hreg[r];
          hreg[r] = hn;
          ydst[(size_t)row * Hn + col] = f2bf(hn);
          if (t == SEQn - 1)
            hT[(role == 0 ? 0 : BHn) + (size_t)row * Hn + col] = hn;
        }
      }
    }
    // ---- device-scope grid barrier (2 cache ops per block per stage) ----
    asm volatile("s_waitcnt vmcnt(0) lgkmcnt(0)" ::: "memory");
    __syncthreads();
    if (tid == 0) {
      __builtin_amdgcn_fence(__ATOMIC_RELEASE, "agent");   // one buffer_wbl2
      __hip_atomic_fetch_add(bar, 1u, __ATOMIC_RELAXED, __HIP_MEMORY_SCOPE_AGENT);
      const unsigned tgt = (unsigned)((s + 1) * NBLK);
      while (__hip_atomic_load(bar, __ATOMIC_RELAXED, __HIP_MEMORY_SCOPE_AGENT) < tgt)
        __builtin_amdgcn_s_sleep(8);
      __builtin_amdgcn_fence(__ATOMIC_ACQUIRE, "agent");   // one buffer_inv
    }
    __syncthreads();
  }
}

// ---------------- launch ----------------

extern "C" void kernel_launch(void* const* d_in, const int* in_sizes, int n_in,
                              void* d_out, int out_size, void* d_ws, size_t ws_size,
                              hipStream_t stream)
{
  (void)in_sizes; (void)n_in; (void)out_size; (void)ws_size;
  const int*   inp    = (const int*)d_in[0];
  const float* hidden = (const float*)d_in[1];
  const float* embW   = (const float*)d_in[2];
  const float* outW   = (const float*)d_in[3];
  const float* outb   = (const float*)d_in[4];

  char* p = (char*)d_ws;
  auto take = [&](size_t n){ char* q = p; p += (n + 255) & ~(size_t)255; return q; };
  bf16*  l0Wi = (bf16*) take((size_t)H3n*En*2);
  bf16*  l0Wh = (bf16*) take((size_t)H3n*Hn*2);
  bf16*  l1Wi = (bf16*) take((size_t)H3n*Hn*2);
  bf16*  l1Wh = (bf16*) take((size_t)H3n*Hn*2);
  bf16*  oW   = (bf16*) take((size_t)VPADn*Hn*2);
  float* b0   = (float*)take((size_t)H3n*4);
  float* b1   = (float*)take((size_t)H3n*4);
  bf16*  emb  = (bf16*) take((size_t)Mn*En*2);
  bf16*  xg   = (bf16*) take((size_t)Mn*H3n*2);
  bf16*  ys0  = (bf16*) take((size_t)(SEQn+1)*BHn*2);
  bf16*  ys1  = (bf16*) take((size_t)(SEQn+1)*BHn*2);
  unsigned* bar = (unsigned*)take(256);

  // weight/bias prep (bf16, gate-concatenated [r;z;h])
  cat3_w<<<dim3((3*Hn*En+255)/256),256,0,stream>>>((const float*)d_in[5],(const float*)d_in[6],(const float*)d_in[7], l0Wi, Hn*En);
  cat3_w<<<dim3((3*Hn*Hn+255)/256),256,0,stream>>>((const float*)d_in[8],(const float*)d_in[9],(const float*)d_in[10], l0Wh, Hn*Hn);
  cat3_w<<<dim3((3*Hn*Hn+255)/256),256,0,stream>>>((const float*)d_in[14],(const float*)d_in[15],(const float*)d_in[16], l1Wi, Hn*Hn);
  cat3_w<<<dim3((3*Hn*Hn+255)/256),256,0,stream>>>((const float*)d_in[17],(const float*)d_in[18],(const float*)d_in[19], l1Wh, Hn*Hn);
  conv_outw<<<dim3((unsigned)(((long)VPADn*Hn+255)/256)),256,0,stream>>>(outW, oW);
  cat3_f<<<dim3((H3n+255)/256),256,0,stream>>>((const float*)d_in[11],(const float*)d_in[12],(const float*)d_in[13], b0, Hn);
  cat3_f<<<dim3((H3n+255)/256),256,0,stream>>>((const float*)d_in[20],(const float*)d_in[21],(const float*)d_in[22], b1, Hn);
  f2b_k<<<dim3((BHn+255)/256),256,0,stream>>>(hidden, ys0, BHn);          // ys0 slot 0 = h0 init
  f2b_k<<<dim3((BHn+255)/256),256,0,stream>>>(hidden + BHn, ys1, BHn);    // ys1 slot 0 = h1 init
  embed_k<<<dim3(Mn),256,0,stream>>>(inp, embW, emb);
  hipMemsetAsync(bar, 0, 256, stream);

  // layer-0 input projection (xg slots hold xg0; role 1 overwrites per-stage)
  gemm_bt<true,false><<<dim3(H3n/128, Mn/128),256,0,stream>>>(emb, l0Wi, b0, xg, En, H3n, H3n);

  // both recurrences + layer-1 input projection, fully pipelined
  float* hT = (float*)d_out + (size_t)SEQn * Bn * Vn;
  gru_persist<<<dim3(NBLK), 512, 0, stream>>>(l0Wh, l1Wi, l1Wh, b1, hidden,
                                              xg, ys0, ys1, hT, bar);

  // logits: ys1 slots 1..70 are h1[0..69]
  gemm_bt<false,true><<<dim3(VPADn/128, Mn/128),256,0,stream>>>(ys1 + BHn, oW, outb, d_out, Hn, Vn, Vn);
}

// Round 4
// 1113.288 us; speedup vs baseline: 5.3707x; 1.6313x over previous
//
#include <hip/hip_runtime.h>
#include <hip/hip_bf16.h>

#define SEQn 70
#define Bn 128
#define En 512
#define Hn 1024
#define Vn 10000
#define VPADn 10240
#define Mn (SEQn*Bn)      // 8960
#define H3n (3*Hn)        // 3072
#define BHn (Bn*Hn)       // 131072
#define NBLK 192

typedef __hip_bfloat16 bf16;
typedef __attribute__((ext_vector_type(8))) short short8;
typedef __attribute__((ext_vector_type(4))) float f32x4;

__device__ __forceinline__ bf16 f2bf(float x){ return __float2bfloat16(x); }
__device__ __forceinline__ float bf2f(bf16 x){ return __bfloat162float(x); }

__device__ __forceinline__ void gl_lds16(const void* g, void* l){
  __builtin_amdgcn_global_load_lds((const __attribute__((address_space(1))) unsigned int*)g,
                                   (__attribute__((address_space(3))) unsigned int*)l, 16, 0, 0);
}

// ---------------- small prep kernels ----------------

__global__ void cat3_w(const float* __restrict__ a, const float* __restrict__ b,
                       const float* __restrict__ c, bf16* __restrict__ d, int n){
  int i = blockIdx.x * 256 + threadIdx.x;
  if (i >= 3*n) return;
  const float* s = (i < n) ? a : ((i < 2*n) ? b : c);
  int off = (i < n) ? i : ((i < 2*n) ? i - n : i - 2*n);
  d[i] = f2bf(s[off]);
}

__global__ void cat3_f(const float* __restrict__ a, const float* __restrict__ b,
                       const float* __restrict__ c, float* __restrict__ d, int n){
  int i = blockIdx.x * 256 + threadIdx.x;
  if (i >= 3*n) return;
  d[i] = (i < n) ? a[i] : ((i < 2*n) ? b[i - n] : c[i - 2*n]);
}

__global__ void f2b_k(const float* __restrict__ s, bf16* __restrict__ d, int n){
  int i = blockIdx.x * 256 + threadIdx.x;
  if (i < n) d[i] = f2bf(s[i]);
}

__global__ void conv_outw(const float* __restrict__ s, bf16* __restrict__ d){
  long i = (long)blockIdx.x * 256 + threadIdx.x;
  if (i >= (long)VPADn * Hn) return;
  int row = (int)(i >> 10);
  d[i] = (row < Vn) ? f2bf(s[i]) : f2bf(0.f);
}

__global__ void embed_k(const int* __restrict__ idx, const float* __restrict__ eW,
                        bf16* __restrict__ out){
  const int sb = blockIdx.x;
  const int t = idx[sb];
  const float* s = eW + (long)t * En;
  bf16* d = out + (long)sb * En;
  for (int e = threadIdx.x; e < En; e += 256) d[e] = f2bf(s[e]);
}

// ---------------- GEMM: C[M,N] = A[M,K] * B[N,K]^T + bias ----------------

template<bool OB, bool NB>
__global__ __launch_bounds__(256)
void gemm_bt(const bf16* __restrict__ A, const bf16* __restrict__ Bm,
             const float* __restrict__ bias, void* __restrict__ C,
             int K, int ldc, int nvalid)
{
  __shared__ __align__(16) bf16 As[128*64];
  __shared__ __align__(16) bf16 Bs[128*64];
  const int tid = threadIdx.x;
  const int l = tid & 63, w = tid >> 6;
  const int lr = l & 15, lk = l >> 4;
  const int wm = (w >> 1) * 64, wn = (w & 1) * 64;
  const int mt = blockIdx.y, nt = blockIdx.x;
  const bf16* Ag = A + (long)mt * 128 * K;
  const bf16* Bg = Bm + (long)nt * 128 * K;

  f32x4 acc[4][4] = {};

  for (int kb = 0; kb < K; kb += 64) {
#pragma unroll
    for (int r = 0; r < 4; ++r) {
      const int u = r * 256 + tid;
      const int row = u >> 3, kus = (u & 7) ^ (row & 7);
      gl_lds16(Ag + (long)row * K + kb + kus * 8, (char*)As + (r * 256 + w * 64) * 16);
    }
#pragma unroll
    for (int r = 0; r < 4; ++r) {
      const int u = r * 256 + tid;
      const int row = u >> 3, kus = (u & 7) ^ (row & 7);
      gl_lds16(Bg + (long)row * K + kb + kus * 8, (char*)Bs + (r * 256 + w * 64) * 16);
    }
    __syncthreads();
#pragma unroll
    for (int kh = 0; kh < 2; ++kh) {
      const int ku = kh * 4 + lk;
      short8 af[4], bfv[4];
#pragma unroll
      for (int i = 0; i < 4; ++i) {
        const int ar = wm + i * 16 + lr;
        af[i]  = *(const short8*)((const char*)As + ar * 128 + ((ku ^ (ar & 7)) * 16));
        const int br = wn + i * 16 + lr;
        bfv[i] = *(const short8*)((const char*)Bs + br * 128 + ((ku ^ (br & 7)) * 16));
      }
#pragma unroll
      for (int i = 0; i < 4; ++i)
#pragma unroll
        for (int j = 0; j < 4; ++j)
          acc[i][j] = __builtin_amdgcn_mfma_f32_16x16x32_bf16(af[i], bfv[j], acc[i][j], 0, 0, 0);
    }
    __syncthreads();
  }

#pragma unroll
  for (int i = 0; i < 4; ++i) {
#pragma unroll
    for (int j = 0; j < 4; ++j) {
      const int col = nt * 128 + wn + j * 16 + lr;
      const bool cok = (!NB) || (col < nvalid);
      const float bv = cok ? bias[col] : 0.f;
      const int row = mt * 128 + wm + i * 16 + lk * 4;
      if (cok) {
#pragma unroll
        for (int r = 0; r < 4; ++r) {
          const float v = acc[i][j][r] + bv;
          if (OB) ((bf16*)C)[(long)(row + r) * ldc + col] = f2bf(v);
          else    ((float*)C)[(long)(row + r) * ldc + col] = v;
        }
      }
    }
  }
}

// ---------------- persistent pipelined GRU ----------------
// 192 blocks x 512 threads. Role = blockIdx.x/64:
//   0: layer-0 recurrence (t=s)   1: layer-1 input proj (t=s-1)
//   2: layer-1 recurrence (t=s-2)
// Weights (48x1024) LDS-resident. h carried in registers.
// Coherence: producers store h/xg1 via relaxed AGENT atomics (sc0sc1
// write-through to MALL, no dirty L2). Consumers read h with PLAIN loads
// (lines written exactly once before first read -> clean L2 copies are
// always the right data; per-XCD L2 hits for 23 of 24 blocks).
// Exception: xg slot t is read (normal) by role-0 at stage t, overwritten
// at t+1, re-read by role-2 at t+2 -> role-2 reads xg via AGENT loads.
// Barrier: per-XCD local arrive (plain L2 atomic, XCD id from
// s_getreg(HW_REG_XCC_ID)) + leaders add their XCD count to a MALL counter
// + single release flag polled with relaxed agent loads. No fences.

#define LOADQ(buf, base)                                                     \
  _Pragma("unroll")                                                          \
  for (int q = 0; q < 8; ++q)                                                \
    buf[q] = *(const short8*)(Arow + ((base) + q) * 32 + lk * 8);

#define MFMAQ(buf, base)                                                     \
  _Pragma("unroll")                                                          \
  for (int q = 0; q < 8; ++q) {                                              \
    _Pragma("unroll")                                                        \
    for (int g = 0; g < 3; ++g) {                                            \
      const int brow = g * 16 + lr;                                          \
      const short8 bfrag = *(const short8*)(smem +                           \
          (size_t)(brow * 128 + ((((base) + q) * 4 + lk) ^ (brow & 7))) * 16); \
      acc[g] = __builtin_amdgcn_mfma_f32_16x16x32_bf16(buf[q], bfrag, acc[g], 0, 0, 0); \
    }                                                                        \
  }

__global__ __launch_bounds__(512, 2)
void gru_persist(const bf16* __restrict__ Wh0, const bf16* __restrict__ Wi1,
                 const bf16* __restrict__ Wh1, const float* __restrict__ b1,
                 const float* __restrict__ hidden, bf16* __restrict__ xg,
                 bf16* __restrict__ ys0, bf16* __restrict__ ys1,
                 float* __restrict__ hT, unsigned* __restrict__ bar)
{
  __shared__ __align__(16) char smem[98304];   // 48 x 1024 bf16 weights, swizzled

  const int tid = threadIdx.x;
  const int lane = tid & 63, wid = tid >> 6;
  const int wbase = tid & ~63;
  const int lr = lane & 15, lk = lane >> 4;
  const int role = blockIdx.x >> 6, nb = blockIdx.x & 63;
  const int col0 = nb * 16;
  const int col = col0 + lr;

  unsigned myxcd;
  asm("s_getreg_b32 %0, hwreg(20, 0, 32)" : "=s"(myxcd));   // HW_REG_XCC_ID
  myxcd &= 7;
  unsigned* larrp  = bar + myxcd * 64;   // per-XCD arrive counter (local L2)
  unsigned* gbarp  = bar + 512;          // global arrive counter (MALL)
  unsigned* gflagp = bar + 544;          // global release flag  (MALL)

  // preload 48x1024 bf16 weight slice into LDS (swizzled: unit ^= row&7)
  const bf16* Wsrc = (role == 0) ? Wh0 : ((role == 1) ? Wi1 : Wh1);
#pragma unroll
  for (int it = 0; it < 12; ++it) {
    const int L = it * 512 + tid;
    const int row = L >> 7, up = L & 127, u = up ^ (row & 7);
    const int g3 = row >> 4, rr = row & 15;
    gl_lds16(Wsrc + ((size_t)(g3 * Hn + col0 + rr)) * Hn + (size_t)u * 8,
             smem + (it * 512 + wbase) * 16);
  }

  f32x4 hreg = {};
  float bv[3] = {};
  if (role != 1) {
    const float* hsrc = hidden + (role == 2 ? BHn : 0);
#pragma unroll
    for (int r = 0; r < 4; ++r)
      hreg[r] = hsrc[(size_t)(wid * 16 + lk * 4 + r) * Hn + col];
  } else {
#pragma unroll
    for (int g = 0; g < 3; ++g) bv[g] = b1[g * Hn + col];
  }
  asm volatile("s_waitcnt vmcnt(0)" ::: "memory");
  __syncthreads();

  // ---- init barrier: learn this XCD's block count ----
  unsigned perxcd = 0;
  if (tid == 0) {
    (void)__hip_atomic_fetch_add(larrp, 1u, __ATOMIC_RELAXED, __HIP_MEMORY_SCOPE_WORKGROUP);
    asm volatile("s_waitcnt vmcnt(0)" ::: "memory");
    unsigned g = __hip_atomic_fetch_add(gbarp, 1u, __ATOMIC_RELAXED, __HIP_MEMORY_SCOPE_AGENT);
    if (g == NBLK - 1)
      __hip_atomic_store(gflagp, 1u, __ATOMIC_RELAXED, __HIP_MEMORY_SCOPE_AGENT);
    while (__hip_atomic_load(gflagp, __ATOMIC_RELAXED, __HIP_MEMORY_SCOPE_AGENT) < 1u)
      __builtin_amdgcn_s_sleep(2);
    perxcd = __hip_atomic_fetch_add(larrp, 0u, __ATOMIC_RELAXED, __HIP_MEMORY_SCOPE_WORKGROUP);
  }
  __syncthreads();

  const int arow = wid * 16 + lr;

  for (int s = 0; s < 72; ++s) {
    const int t = s - role;
    if (t >= 0 && t < SEQn) {
      const bf16* Asrc = (role == 0) ? (ys0 + (size_t)t * BHn)
                       : (role == 1) ? (ys0 + (size_t)(t + 1) * BHn)
                                     : (ys1 + (size_t)t * BHn);
      const bf16* Arow = Asrc + (size_t)arow * Hn;
      f32x4 acc[3] = {};
      short8 aA[8], aB[8];
      unsigned short xus[12];
      LOADQ(aA, 0)
      LOADQ(aB, 8)
      if (role != 1) {
        // prefetch the xg slice now; latency hides under the MFMA chain
        const bf16* xsrc = xg + (size_t)t * Bn * (size_t)H3n;
#pragma unroll
        for (int g = 0; g < 3; ++g)
#pragma unroll
          for (int r = 0; r < 4; ++r) {
            const int row = wid * 16 + lk * 4 + r;
            const unsigned short* p =
                (const unsigned short*)(xsrc + (size_t)row * H3n + g * Hn + col);
            xus[g * 4 + r] = (role == 2)
              ? __hip_atomic_load((unsigned short*)p, __ATOMIC_RELAXED, __HIP_MEMORY_SCOPE_AGENT)
              : *p;
          }
      }
      MFMAQ(aA, 0)
      LOADQ(aA, 16)
      MFMAQ(aB, 8)
      LOADQ(aB, 24)
      MFMAQ(aA, 16)
      MFMAQ(aB, 24)

      // epilogue
      if (role == 1) {
#pragma unroll
        for (int g = 0; g < 3; ++g)
#pragma unroll
          for (int r = 0; r < 4; ++r) {
            const int row = wid * 16 + lk * 4 + r;
            unsigned short v = __builtin_bit_cast(unsigned short, f2bf(acc[g][r] + bv[g]));
            __hip_atomic_store(
                (unsigned short*)&xg[((size_t)t * Bn + row) * H3n + g * Hn + col],
                v, __ATOMIC_RELAXED, __HIP_MEMORY_SCOPE_AGENT);
          }
      } else {
        bf16* ydst = ((role == 0) ? ys0 : ys1) + (size_t)(t + 1) * BHn;
#pragma unroll
        for (int r = 0; r < 4; ++r) {
          const int row = wid * 16 + lk * 4 + r;
          const float xr = bf2f(__builtin_bit_cast(bf16, xus[r]));
          const float xz = bf2f(__builtin_bit_cast(bf16, xus[4 + r]));
          const float xh = bf2f(__builtin_bit_cast(bf16, xus[8 + r]));
          const float rg = 1.f / (1.f + __expf(-(xr + acc[0][r])));
          const float zg = 1.f / (1.f + __expf(-(xz + acc[1][r])));
          const float hc = tanhf(xh + rg * acc[2][r]);
          const float hn = (1.f - zg) * hc + zg * hreg[r];
          hreg[r] = hn;
          unsigned short v = __builtin_bit_cast(unsigned short, f2bf(hn));
          __hip_atomic_store((unsigned short*)&ydst[(size_t)row * Hn + col],
                             v, __ATOMIC_RELAXED, __HIP_MEMORY_SCOPE_AGENT);
          if (t == SEQn - 1)
            hT[(role == 0 ? 0 : BHn) + (size_t)row * Hn + col] = hn;
        }
      }
    }
    // ---- hierarchical grid barrier (no cache-maintenance ops) ----
    if (s < 71) {
      __syncthreads();    // emits per-wave s_waitcnt vmcnt(0) before s_barrier
      if (tid == 0) {
        unsigned a = __hip_atomic_fetch_add(larrp, 1u, __ATOMIC_RELAXED,
                                            __HIP_MEMORY_SCOPE_WORKGROUP);
        if (a == perxcd * (unsigned)(s + 2) - 1u) {           // XCD-last this stage
          unsigned g = __hip_atomic_fetch_add(gbarp, perxcd, __ATOMIC_RELAXED,
                                              __HIP_MEMORY_SCOPE_AGENT);
          if (g + perxcd == (unsigned)NBLK * (unsigned)(s + 2))  // device-last
            __hip_atomic_store(gflagp, (unsigned)(s + 2), __ATOMIC_RELAXED,
                               __HIP_MEMORY_SCOPE_AGENT);
        }
        while (__hip_atomic_load(gflagp, __ATOMIC_RELAXED,
                                 __HIP_MEMORY_SCOPE_AGENT) < (unsigned)(s + 2))
          __builtin_amdgcn_s_sleep(2);
      }
      __syncthreads();
    }
  }
}

// ---------------- launch ----------------

extern "C" void kernel_launch(void* const* d_in, const int* in_sizes, int n_in,
                              void* d_out, int out_size, void* d_ws, size_t ws_size,
                              hipStream_t stream)
{
  (void)in_sizes; (void)n_in; (void)out_size; (void)ws_size;
  const int*   inp    = (const int*)d_in[0];
  const float* hidden = (const float*)d_in[1];
  const float* embW   = (const float*)d_in[2];
  const float* outW   = (const float*)d_in[3];
  const float* outb   = (const float*)d_in[4];

  char* p = (char*)d_ws;
  auto take = [&](size_t n){ char* q = p; p += (n + 255) & ~(size_t)255; return q; };
  bf16*  l0Wi = (bf16*) take((size_t)H3n*En*2);
  bf16*  l0Wh = (bf16*) take((size_t)H3n*Hn*2);
  bf16*  l1Wi = (bf16*) take((size_t)H3n*Hn*2);
  bf16*  l1Wh = (bf16*) take((size_t)H3n*Hn*2);
  bf16*  oW   = (bf16*) take((size_t)VPADn*Hn*2);
  float* b0   = (float*)take((size_t)H3n*4);
  float* b1   = (float*)take((size_t)H3n*4);
  bf16*  emb  = (bf16*) take((size_t)Mn*En*2);
  bf16*  xg   = (bf16*) take((size_t)Mn*H3n*2);
  bf16*  ys0  = (bf16*) take((size_t)(SEQn+1)*BHn*2);
  bf16*  ys1  = (bf16*) take((size_t)(SEQn+1)*BHn*2);
  unsigned* bar = (unsigned*)take(4096);

  // weight/bias prep (bf16, gate-concatenated [r;z;h])
  cat3_w<<<dim3((3*Hn*En+255)/256),256,0,stream>>>((const float*)d_in[5],(const float*)d_in[6],(const float*)d_in[7], l0Wi, Hn*En);
  cat3_w<<<dim3((3*Hn*Hn+255)/256),256,0,stream>>>((const float*)d_in[8],(const float*)d_in[9],(const float*)d_in[10], l0Wh, Hn*Hn);
  cat3_w<<<dim3((3*Hn*Hn+255)/256),256,0,stream>>>((const float*)d_in[14],(const float*)d_in[15],(const float*)d_in[16], l1Wi, Hn*Hn);
  cat3_w<<<dim3((3*Hn*Hn+255)/256),256,0,stream>>>((const float*)d_in[17],(const float*)d_in[18],(const float*)d_in[19], l1Wh, Hn*Hn);
  conv_outw<<<dim3((unsigned)(((long)VPADn*Hn+255)/256)),256,0,stream>>>(outW, oW);
  cat3_f<<<dim3((H3n+255)/256),256,0,stream>>>((const float*)d_in[11],(const float*)d_in[12],(const float*)d_in[13], b0, Hn);
  cat3_f<<<dim3((H3n+255)/256),256,0,stream>>>((const float*)d_in[20],(const float*)d_in[21],(const float*)d_in[22], b1, Hn);
  f2b_k<<<dim3((BHn+255)/256),256,0,stream>>>(hidden, ys0, BHn);          // ys0 slot 0 = h0 init
  f2b_k<<<dim3((BHn+255)/256),256,0,stream>>>(hidden + BHn, ys1, BHn);    // ys1 slot 0 = h1 init
  embed_k<<<dim3(Mn),256,0,stream>>>(inp, embW, emb);
  hipMemsetAsync(bar, 0, 4096, stream);

  // layer-0 input projection (xg slots hold xg0; role 1 overwrites per-stage)
  gemm_bt<true,false><<<dim3(H3n/128, Mn/128),256,0,stream>>>(emb, l0Wi, b0, xg, En, H3n, H3n);

  // both recurrences + layer-1 input projection, fully pipelined
  float* hT = (float*)d_out + (size_t)SEQn * Bn * Vn;
  gru_persist<<<dim3(NBLK), 512, 0, stream>>>(l0Wh, l1Wi, l1Wh, b1, hidden,
                                              xg, ys0, ys1, hT, bar);

  // logits: ys1 slots 1..70 are h1[0..69]
  gemm_bt<false,true><<<dim3(VPADn/128, Mn/128),256,0,stream>>>(ys1 + BHn, oW, outb, d_out, Hn, Vn, Vn);
}